// Round 1
// 3482.327 us; speedup vs baseline: 2.1431x; 2.1431x over previous
//
#include <hip/hip_runtime.h>
#include <hip/hip_bf16.h>

typedef __attribute__((ext_vector_type(8))) short short8_t;
typedef __attribute__((ext_vector_type(4))) float floatx4;

#define TSTEPS 256
#define BATCH  256
#define HID    1024

// workspace byte offsets
#define WS_WI  0u          // Wi bf16, 1024*1024*2 = 2 MB
#define WS_WHP 2097152u    // Wh bf16, repacked into MFMA B-fragment order, 2 MB
#define WS_BAR 4194304u    // 8 group barrier counters, padded to 128 B each (1 KB)

static __device__ __forceinline__ unsigned short f2bf(float f) {
    union { float f; unsigned int u; } v; v.f = f;
    unsigned int u = v.u;
    u += 0x7fffu + ((u >> 16) & 1u);   // RNE
    return (unsigned short)(u >> 16);
}

// ---------------- prep: Wi fp32->bf16; Wh fp32->bf16 repacked fragment-major; zero barriers ----
// Whp flat index: (((colt*32 + kt)*4 + quad)*16 + l15)*8 + e
//   col = colt*16 + l15, k = kt*32 + quad*8 + e
__global__ void prep_kernel(const float* __restrict__ Wi, const float* __restrict__ Wh,
                            unsigned short* __restrict__ wi_bf,
                            unsigned short* __restrict__ whp,
                            unsigned int* __restrict__ bar) {
    unsigned int idx = blockIdx.x * 256u + threadIdx.x;
    if (idx < 256u) bar[idx] = 0u;               // re-zeroed every launch (graph replay safe)
    if (idx < 1048576u) {
        wi_bf[idx] = f2bf(Wi[idx]);
    } else {
        unsigned int o = idx - 1048576u;
        unsigned int e    = o & 7u;
        unsigned int l15  = (o >> 3) & 15u;
        unsigned int quad = (o >> 7) & 3u;
        unsigned int kt   = (o >> 9) & 31u;
        unsigned int colt = o >> 14;
        unsigned int col = colt * 16u + l15;
        unsigned int k   = kt * 32u + quad * 8u + e;
        whp[o] = f2bf(Wh[col * 1024u + k]);
    }
}

// ---------------- xi = x @ Wi^T + bi  (M=65536, N=1024, K=1024) ---------------- (unchanged)
__global__ __launch_bounds__(256) void xi_gemm(
    const float* __restrict__ X,
    const unsigned short* __restrict__ Wi_bf,
    const float* __restrict__ Wi_b,
    float* __restrict__ Out) {
    __shared__ unsigned short As[128][40];
    __shared__ unsigned short Bs[128][40];

    int tid = threadIdx.x;
    int bx = blockIdx.x;
    int bm = bx >> 3, bn = bx & 7;
    int wave = tid >> 6, lane = tid & 63, l15 = lane & 15, quad = lane >> 4;
    int mw = (wave >> 1) * 64, nw = (wave & 1) * 64;

    floatx4 acc[4][4];
#pragma unroll
    for (int i = 0; i < 4; ++i)
#pragma unroll
        for (int j = 0; j < 4; ++j) acc[i][j] = (floatx4){0.f, 0.f, 0.f, 0.f};

    int srow = tid >> 1;
    int shalf = tid & 1;
    const float* ap = X + (long)(bm * 128 + srow) * 1024 + shalf * 16;
    const unsigned short* bp = Wi_bf + (long)(bn * 128 + srow) * 1024 + shalf * 16;
    unsigned short* asw = &As[srow][shalf * 16];
    unsigned short* bsw = &Bs[srow][shalf * 16];

    for (int kt = 0; kt < 32; ++kt) {
        float4 a0 = *(const float4*)(ap + 0);
        float4 a1 = *(const float4*)(ap + 4);
        float4 a2 = *(const float4*)(ap + 8);
        float4 a3 = *(const float4*)(ap + 12);
        short8_t b0 = *(const short8_t*)(bp);
        short8_t b1 = *(const short8_t*)(bp + 8);
        ap += 32; bp += 32;

        short8_t av0, av1;
        av0[0] = (short)f2bf(a0.x); av0[1] = (short)f2bf(a0.y);
        av0[2] = (short)f2bf(a0.z); av0[3] = (short)f2bf(a0.w);
        av0[4] = (short)f2bf(a1.x); av0[5] = (short)f2bf(a1.y);
        av0[6] = (short)f2bf(a1.z); av0[7] = (short)f2bf(a1.w);
        av1[0] = (short)f2bf(a2.x); av1[1] = (short)f2bf(a2.y);
        av1[2] = (short)f2bf(a2.z); av1[3] = (short)f2bf(a2.w);
        av1[4] = (short)f2bf(a3.x); av1[5] = (short)f2bf(a3.y);
        av1[6] = (short)f2bf(a3.z); av1[7] = (short)f2bf(a3.w);

        *(short8_t*)asw = av0;
        *(short8_t*)(asw + 8) = av1;
        *(short8_t*)bsw = b0;
        *(short8_t*)(bsw + 8) = b1;
        __syncthreads();

        short8_t aF[4], bF[4];
#pragma unroll
        for (int i = 0; i < 4; ++i) aF[i] = *(const short8_t*)&As[mw + i * 16 + l15][quad * 8];
#pragma unroll
        for (int i = 0; i < 4; ++i) bF[i] = *(const short8_t*)&Bs[nw + i * 16 + l15][quad * 8];
#pragma unroll
        for (int i = 0; i < 4; ++i)
#pragma unroll
            for (int j = 0; j < 4; ++j)
                acc[i][j] = __builtin_amdgcn_mfma_f32_16x16x32_bf16(aF[i], bF[j], acc[i][j], 0, 0, 0);
        __syncthreads();
    }

    long rowbase = (long)bm * 128 + mw + quad * 4;
    int colbase = bn * 128 + nw + l15;
#pragma unroll
    for (int j = 0; j < 4; ++j) {
        float bias = Wi_b[colbase + j * 16];
#pragma unroll
        for (int i = 0; i < 4; ++i)
#pragma unroll
            for (int r = 0; r < 4; ++r)
                Out[(rowbase + i * 16 + r) * 1024 + colbase + j * 16] = acc[i][j][r] + bias;
    }
}

// ---------------- recurrent scan v2: 256 WGs (one per CU) ----------------
// Decomposition: 8 batch groups (32 rows) x 32 col groups (32 cols).
//   g  = blockIdx & 7   -> under round-robin dispatch all 32 WGs of a group land on one XCD
//   cg = blockIdx >> 3
// Wh column slice (64 KB) persistent in LDS; h(t) staged per step from global fp32
// (the kernel's own output IO[t-1]) into swizzled bf16 LDS; per-group spin barrier
// with agent-scope release/acquire fences (correct independent of XCD placement).
__global__ __launch_bounds__(256, 1) void rnn_scan2(
    float* __restrict__ IO,                       // xi in, h out (in-place)
    const unsigned short* __restrict__ whp,       // fragment-packed Wh bf16
    const float* __restrict__ Wh_b,
    const float* __restrict__ h0,
    unsigned int* __restrict__ bar) {
    __shared__ __align__(16) char smem[131072];
    unsigned short* whs = (unsigned short*)smem;  // 64 KB: [2 colt][32 kt][512] fragment-packed
    char* hs = smem + 65536;                      // 64 KB: 32 rows x 2048 B, XOR-swizzled

    const int bid = blockIdx.x;
    const int g   = bid & 7;                      // batch group: rows g*32 .. g*32+31
    const int cg  = bid >> 3;                     // col group:   cols cg*32 .. cg*32+31
    const int tid = threadIdx.x;
    const int wave = tid >> 6, lane = tid & 63, l15 = lane & 15, quad = lane >> 4;
    const int wr = wave >> 1, wc = wave & 1;      // 2x2 16x16 tiles, one per wave

    // ---- Wh slice -> LDS: contiguous 32768 shorts (2 col-tiles worth) ----
    {
        const short8_t* src = (const short8_t*)(whp + (unsigned)cg * 32768u);
        short8_t* dst = (short8_t*)whs;
        for (int i = tid; i < 4096; i += 256) dst[i] = src[i];
    }

    unsigned int* cnt = bar + (unsigned)g * 32u;  // 128 B padding between groups

    const int col_g = cg * 32 + wc * 16 + l15;
    const float bias = Wh_b[col_g];

    // B-fragment base: whs + wc*16384 + kt*512 + lane*8 (contiguous 16 B/lane, conflict-free)
    const unsigned short* wB = whs + (unsigned)wc * 16384u + (unsigned)lane * 8u;
    // A-fragment: row arow, k-chunk quad*8 within each kt tile (swizzled, bank-balanced)
    const int arow = wr * 16 + l15;
    const char* aptr = hs + arow * 2048;
    const unsigned int a_xor = (unsigned)((arow & 7) << 4);
    const unsigned int q16 = (unsigned)(quad * 16);

    const long rowb = (long)(g * 32 + wr * 16 + quad * 4) * 1024 + col_g;

    for (int t = 0; t < TSTEPS; ++t) {
        const long ob = (long)t * (BATCH * HID) + rowb;
        // xi prefetch (WG-private tile of IO[t]; hides L2/HBM latency under staging)
        float x0 = IO[ob], x1 = IO[ob + 1024], x2 = IO[ob + 2048], x3 = IO[ob + 3072];

        // ---- stage h(t): 32 rows x 1024 fp32 -> bf16 swizzled LDS ----
        const float* hb = (t == 0) ? (h0 + (long)g * 32 * 1024)
                                   : (IO + (long)(t - 1) * (BATCH * HID) + (long)g * 32 * 1024);
#pragma unroll
        for (int rr = 0; rr < 8; ++rr) {
            const int rl = wave * 8 + rr;                    // local row 0..31
            const float* sp = hb + (long)rl * 1024 + lane * 8;
            const unsigned int sw = (unsigned)((rl & 7) << 4);
            char* db = hs + rl * 2048;
            float4 a0 = *(const float4*)(sp);
            float4 a1 = *(const float4*)(sp + 4);
            float4 b0 = *(const float4*)(sp + 512);
            float4 b1 = *(const float4*)(sp + 516);
            short8_t v0, v1;
            v0[0] = (short)f2bf(a0.x); v0[1] = (short)f2bf(a0.y);
            v0[2] = (short)f2bf(a0.z); v0[3] = (short)f2bf(a0.w);
            v0[4] = (short)f2bf(a1.x); v0[5] = (short)f2bf(a1.y);
            v0[6] = (short)f2bf(a1.z); v0[7] = (short)f2bf(a1.w);
            v1[0] = (short)f2bf(b0.x); v1[1] = (short)f2bf(b0.y);
            v1[2] = (short)f2bf(b0.z); v1[3] = (short)f2bf(b0.w);
            v1[4] = (short)f2bf(b1.x); v1[5] = (short)f2bf(b1.y);
            v1[6] = (short)f2bf(b1.z); v1[7] = (short)f2bf(b1.w);
            *(short8_t*)(db + (((unsigned)(lane * 16)) ^ sw)) = v0;
            *(short8_t*)(db + (((unsigned)(1024 + lane * 16)) ^ sw)) = v1;
        }
        __syncthreads();

        // ---- 16x16 tile GEMM over K=1024 (32 MFMAs, 2 accumulators) ----
        floatx4 acc0 = (floatx4){0.f, 0.f, 0.f, 0.f};
        floatx4 acc1 = (floatx4){0.f, 0.f, 0.f, 0.f};
#pragma unroll
        for (int kt = 0; kt < 32; kt += 2) {
            short8_t af0 = *(const short8_t*)(aptr + (((unsigned)(kt * 64) + q16) ^ a_xor));
            short8_t bf0 = *(const short8_t*)(wB + (unsigned)kt * 512u);
            acc0 = __builtin_amdgcn_mfma_f32_16x16x32_bf16(af0, bf0, acc0, 0, 0, 0);
            short8_t af1 = *(const short8_t*)(aptr + (((unsigned)((kt + 1) * 64) + q16) ^ a_xor));
            short8_t bf1 = *(const short8_t*)(wB + (unsigned)(kt + 1) * 512u);
            acc1 = __builtin_amdgcn_mfma_f32_16x16x32_bf16(af1, bf1, acc1, 0, 0, 0);
        }
        floatx4 aa = acc0 + acc1;

        // ---- epilogue: h = tanh(acc + xi + bias), fp32 out (doubles as h(t+1) source) ----
        IO[ob]        = tanhf(aa[0] + x0 + bias);
        IO[ob + 1024] = tanhf(aa[1] + x1 + bias);
        IO[ob + 2048] = tanhf(aa[2] + x2 + bias);
        IO[ob + 3072] = tanhf(aa[3] + x3 + bias);

        // ---- per-group barrier: all 32 col-WGs of group g ----
        __syncthreads();   // drains every thread's stores (vmcnt 0) + protects hs reuse
        if (t < TSTEPS - 1) {
            if (tid == 0) {
                __builtin_amdgcn_fence(__ATOMIC_RELEASE, "agent");   // L2 writeback -> visible
                __hip_atomic_fetch_add(cnt, 1u, __ATOMIC_RELAXED, __HIP_MEMORY_SCOPE_AGENT);
                const unsigned int tgt = 32u * (unsigned)(t + 1);    // monotonic, no reset races
                while (__hip_atomic_load(cnt, __ATOMIC_RELAXED, __HIP_MEMORY_SCOPE_AGENT) < tgt)
                    __builtin_amdgcn_s_sleep(2);
                __builtin_amdgcn_fence(__ATOMIC_ACQUIRE, "agent");   // invalidate stale L1/L2
            }
            __syncthreads();
        }
    }
}

extern "C" void kernel_launch(void* const* d_in, const int* in_sizes, int n_in,
                              void* d_out, int out_size, void* d_ws, size_t ws_size,
                              hipStream_t stream) {
    const float* x    = (const float*)d_in[0];
    const float* h0   = (const float*)d_in[1];
    const float* Wi_w = (const float*)d_in[2];
    const float* Wi_b = (const float*)d_in[3];
    const float* Wh_w = (const float*)d_in[4];
    const float* Wh_b = (const float*)d_in[5];
    float* out = (float*)d_out;
    char* ws = (char*)d_ws;
    unsigned short* wi_bf = (unsigned short*)(ws + WS_WI);
    unsigned short* whp   = (unsigned short*)(ws + WS_WHP);
    unsigned int*   bar   = (unsigned int*)(ws + WS_BAR);

    prep_kernel<<<8192, 256, 0, stream>>>(Wi_w, Wh_w, wi_bf, whp, bar);
    xi_gemm<<<4096, 256, 0, stream>>>(x, wi_bf, Wi_b, out);
    // 256 WGs == CU count; 128 KB LDS + __launch_bounds__(256,1) -> exactly 1 WG/CU,
    // so all groups' WGs are co-resident (required for the spin barrier).
    rnn_scan2<<<256, 256, 0, stream>>>(out, whp, Wh_b, h0, bar);
}

// Round 2
// 3126.545 us; speedup vs baseline: 2.3870x; 1.1138x over previous
//
#include <hip/hip_runtime.h>
#include <hip/hip_bf16.h>

typedef __attribute__((ext_vector_type(8))) short short8_t;
typedef __attribute__((ext_vector_type(4))) float floatx4;

#define TSTEPS 256
#define BATCH  256
#define HID    1024

// workspace byte offsets
//   [0 .. 2M)   : wi_bf (bf16 Wi) during prep+xi_gemm; REUSED as hbf during rnn_scan2
//                 (stream-ordered: xi_gemm completes before rnn_scan2 starts)
//                 hbf = 2 bufs x 8 groups x 32 rows x 1024 cols bf16 = 1 MB
//   [2M .. 4M)  : whp (fragment-packed Wh bf16)
//   [4M .. +1K) : barrier counters
#define WS_WI  0u
#define WS_WHP 2097152u
#define WS_BAR 4194304u
#define HBF_BUF_U32 131072u   // 512 KB per buffer, in u32 units
#define HBF_GRP_U32 16384u    // 64 KB per group, in u32 units

static __device__ __forceinline__ unsigned short f2bf(float f) {
    union { float f; unsigned int u; } v; v.f = f;
    unsigned int u = v.u;
    u += 0x7fffu + ((u >> 16) & 1u);   // RNE
    return (unsigned short)(u >> 16);
}

// ---------------- prep: Wi fp32->bf16; Wh fp32->bf16 repacked fragment-major; zero barriers ----
__global__ void prep_kernel(const float* __restrict__ Wi, const float* __restrict__ Wh,
                            unsigned short* __restrict__ wi_bf,
                            unsigned short* __restrict__ whp,
                            unsigned int* __restrict__ bar) {
    unsigned int idx = blockIdx.x * 256u + threadIdx.x;
    if (idx < 256u) bar[idx] = 0u;               // re-zeroed every launch (graph replay safe)
    if (idx < 1048576u) {
        wi_bf[idx] = f2bf(Wi[idx]);
    } else {
        unsigned int o = idx - 1048576u;
        unsigned int e    = o & 7u;
        unsigned int l15  = (o >> 3) & 15u;
        unsigned int quad = (o >> 7) & 3u;
        unsigned int kt   = (o >> 9) & 31u;
        unsigned int colt = o >> 14;
        unsigned int col = colt * 16u + l15;
        unsigned int k   = kt * 32u + quad * 8u + e;
        whp[o] = f2bf(Wh[col * 1024u + k]);
    }
}

// ---------------- xi = x @ Wi^T + bi  (M=65536, N=1024, K=1024) ---------------- (unchanged)
__global__ __launch_bounds__(256) void xi_gemm(
    const float* __restrict__ X,
    const unsigned short* __restrict__ Wi_bf,
    const float* __restrict__ Wi_b,
    float* __restrict__ Out) {
    __shared__ unsigned short As[128][40];
    __shared__ unsigned short Bs[128][40];

    int tid = threadIdx.x;
    int bx = blockIdx.x;
    int bm = bx >> 3, bn = bx & 7;
    int wave = tid >> 6, lane = tid & 63, l15 = lane & 15, quad = lane >> 4;
    int mw = (wave >> 1) * 64, nw = (wave & 1) * 64;

    floatx4 acc[4][4];
#pragma unroll
    for (int i = 0; i < 4; ++i)
#pragma unroll
        for (int j = 0; j < 4; ++j) acc[i][j] = (floatx4){0.f, 0.f, 0.f, 0.f};

    int srow = tid >> 1;
    int shalf = tid & 1;
    const float* ap = X + (long)(bm * 128 + srow) * 1024 + shalf * 16;
    const unsigned short* bp = Wi_bf + (long)(bn * 128 + srow) * 1024 + shalf * 16;
    unsigned short* asw = &As[srow][shalf * 16];
    unsigned short* bsw = &Bs[srow][shalf * 16];

    for (int kt = 0; kt < 32; ++kt) {
        float4 a0 = *(const float4*)(ap + 0);
        float4 a1 = *(const float4*)(ap + 4);
        float4 a2 = *(const float4*)(ap + 8);
        float4 a3 = *(const float4*)(ap + 12);
        short8_t b0 = *(const short8_t*)(bp);
        short8_t b1 = *(const short8_t*)(bp + 8);
        ap += 32; bp += 32;

        short8_t av0, av1;
        av0[0] = (short)f2bf(a0.x); av0[1] = (short)f2bf(a0.y);
        av0[2] = (short)f2bf(a0.z); av0[3] = (short)f2bf(a0.w);
        av0[4] = (short)f2bf(a1.x); av0[5] = (short)f2bf(a1.y);
        av0[6] = (short)f2bf(a1.z); av0[7] = (short)f2bf(a1.w);
        av1[0] = (short)f2bf(a2.x); av1[1] = (short)f2bf(a2.y);
        av1[2] = (short)f2bf(a2.z); av1[3] = (short)f2bf(a2.w);
        av1[4] = (short)f2bf(a3.x); av1[5] = (short)f2bf(a3.y);
        av1[6] = (short)f2bf(a3.z); av1[7] = (short)f2bf(a3.w);

        *(short8_t*)asw = av0;
        *(short8_t*)(asw + 8) = av1;
        *(short8_t*)bsw = b0;
        *(short8_t*)(bsw + 8) = b1;
        __syncthreads();

        short8_t aF[4], bF[4];
#pragma unroll
        for (int i = 0; i < 4; ++i) aF[i] = *(const short8_t*)&As[mw + i * 16 + l15][quad * 8];
#pragma unroll
        for (int i = 0; i < 4; ++i) bF[i] = *(const short8_t*)&Bs[nw + i * 16 + l15][quad * 8];
#pragma unroll
        for (int i = 0; i < 4; ++i)
#pragma unroll
            for (int j = 0; j < 4; ++j)
                acc[i][j] = __builtin_amdgcn_mfma_f32_16x16x32_bf16(aF[i], bF[j], acc[i][j], 0, 0, 0);
        __syncthreads();
    }

    long rowbase = (long)bm * 128 + mw + quad * 4;
    int colbase = bn * 128 + nw + l15;
#pragma unroll
    for (int j = 0; j < 4; ++j) {
        float bias = Wi_b[colbase + j * 16];
#pragma unroll
        for (int i = 0; i < 4; ++i)
#pragma unroll
            for (int r = 0; r < 4; ++r)
                Out[(rowbase + i * 16 + r) * 1024 + colbase + j * 16] = acc[i][j][r] + bias;
    }
}

// ---------------- recurrent scan v3: fence-free device-coherent h exchange ----------------
// 8 batch groups (32 rows) x 32 col groups (32 cols) = 256 WGs, 1/CU.
// h(t) lives in hbf (bf16, double-buffered, per-group [32][1024]); producers write it with
// relaxed AGENT-scope atomic u32 stores (write-through to MALL), consumers read it with
// relaxed AGENT-scope atomic u32 loads (bypass L1/L2 -> always coherent).
// => NO buffer_wbl2 / buffer_inv per step; __syncthreads (vmcnt drain) + relaxed atomicAdd
//    is a complete release; the spin + __syncthreads is a complete acquire for sc-loads.
// IO fp32 writes stay plain cached stores (never re-read by the scan) and drain lazily.
__global__ __launch_bounds__(256, 1) void rnn_scan2(
    float* __restrict__ IO,                       // xi in, h out (in-place)
    const unsigned short* __restrict__ whp,       // fragment-packed Wh bf16
    const float* __restrict__ Wh_b,
    const float* __restrict__ h0,
    unsigned int* __restrict__ bar,
    unsigned int* __restrict__ hbf) {             // bf16 h exchange buffers (u32-packed)
    __shared__ __align__(16) char smem[131072];
    unsigned short* whs = (unsigned short*)smem;  // 64 KB Wh slice, fragment-packed
    char* hs = smem + 65536;                      // 64 KB: 32 rows x 2048 B, XOR-swizzled

    const int bid = blockIdx.x;
    const int g   = bid & 7;                      // batch group: rows g*32 .. g*32+31
    const int cg  = bid >> 3;                     // col group:   cols cg*32 .. cg*32+31
    const int tid = threadIdx.x;
    const int wave = tid >> 6, lane = tid & 63, l15 = lane & 15, quad = lane >> 4;
    const int wr = wave >> 1, wc = wave & 1;      // 2x2 16x16 tiles, one per wave

    // ---- Wh slice -> LDS ----
    {
        const short8_t* src = (const short8_t*)(whp + (unsigned)cg * 32768u);
        short8_t* dst = (short8_t*)whs;
        for (int i = tid; i < 4096; i += 256) dst[i] = src[i];
    }

    unsigned int* cnt = bar + (unsigned)g * 32u;

    const int col_g = cg * 32 + wc * 16 + l15;    // this lane's output column (0..1023)
    const float bias = Wh_b[col_g];

    const unsigned short* wB = whs + (unsigned)wc * 16384u + (unsigned)lane * 8u;
    const int arow = wr * 16 + l15;
    const char* aptr = hs + arow * 2048;
    const unsigned int a_xor = (unsigned)((arow & 7) << 4);
    const unsigned int q16 = (unsigned)(quad * 16);

    const long rowb = (long)(g * 32 + wr * 16 + quad * 4) * 1024 + col_g;
    const int rowl0 = wr * 16 + quad * 4;         // local row of acc element r=0
    const unsigned int cph = (unsigned)(col_g >> 1);  // u32 col-pair index in hbf row

    long ob = rowb;
    float x0 = IO[ob], x1 = IO[ob + 1024], x2 = IO[ob + 2048], x3 = IO[ob + 3072];

    for (int t = 0; t < TSTEPS; ++t) {
        // ---- stage h(t) into swizzled LDS ----
        if (t == 0) {
            // slow path once: h0 fp32 -> bf16 pack (plain cached loads; h0 pre-launch data)
            const float* hb = h0 + (long)g * 32 * 1024;
#pragma unroll
            for (int rr = 0; rr < 8; ++rr) {
                const int rl = wave * 8 + rr;
                const float* sp = hb + (long)rl * 1024 + lane * 8;
                const unsigned int sw = (unsigned)((rl & 7) << 4);
                char* db = hs + rl * 2048;
                float4 a0 = *(const float4*)(sp);
                float4 a1 = *(const float4*)(sp + 4);
                float4 b0 = *(const float4*)(sp + 512);
                float4 b1 = *(const float4*)(sp + 516);
                short8_t v0, v1;
                v0[0] = (short)f2bf(a0.x); v0[1] = (short)f2bf(a0.y);
                v0[2] = (short)f2bf(a0.z); v0[3] = (short)f2bf(a0.w);
                v0[4] = (short)f2bf(a1.x); v0[5] = (short)f2bf(a1.y);
                v0[6] = (short)f2bf(a1.z); v0[7] = (short)f2bf(a1.w);
                v1[0] = (short)f2bf(b0.x); v1[1] = (short)f2bf(b0.y);
                v1[2] = (short)f2bf(b0.z); v1[3] = (short)f2bf(b0.w);
                v1[4] = (short)f2bf(b1.x); v1[5] = (short)f2bf(b1.y);
                v1[6] = (short)f2bf(b1.z); v1[7] = (short)f2bf(b1.w);
                *(short8_t*)(db + (((unsigned)(lane * 16)) ^ sw)) = v0;
                *(short8_t*)(db + (((unsigned)(1024 + lane * 16)) ^ sw)) = v1;
            }
        } else {
            // fast path: bf16 u32 coherent loads -> uint4 ds_writes (no unpack VALU)
            const unsigned int* hsrc = hbf + (unsigned)(t & 1) * HBF_BUF_U32 + (unsigned)g * HBF_GRP_U32;
#pragma unroll
            for (int rr = 0; rr < 8; ++rr) {
                const int rl = wave * 8 + rr;
                const unsigned int* sp = hsrc + rl * 512 + lane * 8;
                unsigned int d0 = __hip_atomic_load(sp + 0, __ATOMIC_RELAXED, __HIP_MEMORY_SCOPE_AGENT);
                unsigned int d1 = __hip_atomic_load(sp + 1, __ATOMIC_RELAXED, __HIP_MEMORY_SCOPE_AGENT);
                unsigned int d2 = __hip_atomic_load(sp + 2, __ATOMIC_RELAXED, __HIP_MEMORY_SCOPE_AGENT);
                unsigned int d3 = __hip_atomic_load(sp + 3, __ATOMIC_RELAXED, __HIP_MEMORY_SCOPE_AGENT);
                unsigned int d4 = __hip_atomic_load(sp + 4, __ATOMIC_RELAXED, __HIP_MEMORY_SCOPE_AGENT);
                unsigned int d5 = __hip_atomic_load(sp + 5, __ATOMIC_RELAXED, __HIP_MEMORY_SCOPE_AGENT);
                unsigned int d6 = __hip_atomic_load(sp + 6, __ATOMIC_RELAXED, __HIP_MEMORY_SCOPE_AGENT);
                unsigned int d7 = __hip_atomic_load(sp + 7, __ATOMIC_RELAXED, __HIP_MEMORY_SCOPE_AGENT);
                const unsigned int sw = (unsigned)((rl & 7) << 4);
                char* db = hs + rl * 2048;
                uint4 w0; w0.x = d0; w0.y = d1; w0.z = d2; w0.w = d3;
                uint4 w1; w1.x = d4; w1.y = d5; w1.z = d6; w1.w = d7;
                *(uint4*)(db + (((unsigned)(lane * 32)) ^ sw)) = w0;
                *(uint4*)(db + (((unsigned)(lane * 32 + 16)) ^ sw)) = w1;
            }
        }
        __syncthreads();

        // ---- 16x16 tile GEMM over K=1024 (32 MFMAs, 2 accumulators) ----
        floatx4 acc0 = (floatx4){0.f, 0.f, 0.f, 0.f};
        floatx4 acc1 = (floatx4){0.f, 0.f, 0.f, 0.f};
#pragma unroll
        for (int kt = 0; kt < 32; kt += 2) {
            short8_t af0 = *(const short8_t*)(aptr + (((unsigned)(kt * 64) + q16) ^ a_xor));
            short8_t bf0 = *(const short8_t*)(wB + (unsigned)kt * 512u);
            acc0 = __builtin_amdgcn_mfma_f32_16x16x32_bf16(af0, bf0, acc0, 0, 0, 0);
            short8_t af1 = *(const short8_t*)(aptr + (((unsigned)((kt + 1) * 64) + q16) ^ a_xor));
            short8_t bf1 = *(const short8_t*)(wB + (unsigned)(kt + 1) * 512u);
            acc1 = __builtin_amdgcn_mfma_f32_16x16x32_bf16(af1, bf1, acc1, 0, 0, 0);
        }
        floatx4 aa = acc0 + acc1;

        // ---- epilogue: h = tanh(acc + xi + bias) ----
        float hv0 = tanhf(aa[0] + x0 + bias);
        float hv1 = tanhf(aa[1] + x1 + bias);
        float hv2 = tanhf(aa[2] + x2 + bias);
        float hv3 = tanhf(aa[3] + x3 + bias);
        IO[ob]        = hv0;                      // plain cached stores (never re-read)
        IO[ob + 1024] = hv1;
        IO[ob + 2048] = hv2;
        IO[ob + 3072] = hv3;

        if (t < TSTEPS - 1) {
            // ---- publish h(t+1) as bf16 u32 pairs (coherent write-through) ----
            unsigned int b0 = (unsigned int)f2bf(hv0);
            unsigned int b1 = (unsigned int)f2bf(hv1);
            unsigned int b2 = (unsigned int)f2bf(hv2);
            unsigned int b3 = (unsigned int)f2bf(hv3);
            unsigned int p0 = (unsigned int)__shfl_xor((int)b0, 1);
            unsigned int p1 = (unsigned int)__shfl_xor((int)b1, 1);
            unsigned int p2 = (unsigned int)__shfl_xor((int)b2, 1);
            unsigned int p3 = (unsigned int)__shfl_xor((int)b3, 1);
            unsigned int* dpb = hbf + (unsigned)((t + 1) & 1) * HBF_BUF_U32 + (unsigned)g * HBF_GRP_U32;
            if (!(lane & 1)) {                    // even lane: rows r=0,1 (own col low)
                __hip_atomic_store(dpb + (rowl0 + 0) * 512 + cph, b0 | (p0 << 16),
                                   __ATOMIC_RELAXED, __HIP_MEMORY_SCOPE_AGENT);
                __hip_atomic_store(dpb + (rowl0 + 1) * 512 + cph, b1 | (p1 << 16),
                                   __ATOMIC_RELAXED, __HIP_MEMORY_SCOPE_AGENT);
            } else {                              // odd lane: rows r=2,3 (partner col low)
                __hip_atomic_store(dpb + (rowl0 + 2) * 512 + cph, p2 | (b2 << 16),
                                   __ATOMIC_RELAXED, __HIP_MEMORY_SCOPE_AGENT);
                __hip_atomic_store(dpb + (rowl0 + 3) * 512 + cph, p3 | (b3 << 16),
                                   __ATOMIC_RELAXED, __HIP_MEMORY_SCOPE_AGENT);
            }

            __syncthreads();                      // drains all stores (vmcnt 0) + protects hs
            if (tid == 0)                         // arrive
                __hip_atomic_fetch_add(cnt, 1u, __ATOMIC_RELAXED, __HIP_MEMORY_SCOPE_AGENT);
            ob += (long)BATCH * HID;
            x0 = IO[ob]; x1 = IO[ob + 1024];      // xi[t+1] prefetch hides under the spin
            x2 = IO[ob + 2048]; x3 = IO[ob + 3072];
            if (tid == 0) {
                const unsigned int tgt = 32u * (unsigned)(t + 1);
                while (__hip_atomic_load(cnt, __ATOMIC_RELAXED, __HIP_MEMORY_SCOPE_AGENT) < tgt)
                    __builtin_amdgcn_s_sleep(1);
            }
            __syncthreads();
        }
    }
}

extern "C" void kernel_launch(void* const* d_in, const int* in_sizes, int n_in,
                              void* d_out, int out_size, void* d_ws, size_t ws_size,
                              hipStream_t stream) {
    const float* x    = (const float*)d_in[0];
    const float* h0   = (const float*)d_in[1];
    const float* Wi_w = (const float*)d_in[2];
    const float* Wi_b = (const float*)d_in[3];
    const float* Wh_w = (const float*)d_in[4];
    const float* Wh_b = (const float*)d_in[5];
    float* out = (float*)d_out;
    char* ws = (char*)d_ws;
    unsigned short* wi_bf = (unsigned short*)(ws + WS_WI);
    unsigned short* whp   = (unsigned short*)(ws + WS_WHP);
    unsigned int*   bar   = (unsigned int*)(ws + WS_BAR);
    unsigned int*   hbf   = (unsigned int*)(ws + WS_WI);   // overlays wi_bf: dead after xi_gemm

    prep_kernel<<<8192, 256, 0, stream>>>(Wi_w, Wh_w, wi_bf, whp, bar);
    xi_gemm<<<4096, 256, 0, stream>>>(x, wi_bf, Wi_b, out);
    // 256 WGs == CU count; 128 KB LDS + __launch_bounds__(256,1) -> exactly 1 WG/CU,
    // so all groups' WGs are co-resident (required for the spin barrier).
    rnn_scan2<<<256, 256, 0, stream>>>(out, whp, Wh_b, h0, bar, hbf);
}

// Round 3
// 2428.105 us; speedup vs baseline: 3.0736x; 1.2876x over previous
//
#include <hip/hip_runtime.h>
#include <hip/hip_bf16.h>

typedef __attribute__((ext_vector_type(8))) short short8_t;
typedef __attribute__((ext_vector_type(4))) float floatx4;
typedef __attribute__((ext_vector_type(4))) unsigned int uintx4;

#define TSTEPS 256
#define BATCH  256
#define HID    1024

// workspace layout
//   [0      .. 2M)   : wi_bf  (bf16 Wi, used by prep + xi_gemm only)
//   [2M     .. 4M)   : whp    (fragment-packed Wh bf16)
//   [4M     .. +1K)  : flags  (8 groups x 32 WG flags, monotonic step counters)
//   [4M+4K  .. +1M)  : hbf    (bf16 h exchange, 2 bufs x 8 groups x 32 rows x 1024 cols)
#define WS_WI  0u
#define WS_WHP 2097152u
#define WS_BAR 4194304u
#define WS_HBF 4198400u
#define HBF_BUF_U32 131072u   // 512 KB per buffer, in u32 units
#define HBF_GRP_U32 16384u    // 64 KB per group, in u32 units

static __device__ __forceinline__ unsigned short f2bf(float f) {
    union { float f; unsigned int u; } v; v.f = f;
    unsigned int u = v.u;
    u += 0x7fffu + ((u >> 16) & 1u);   // RNE
    return (unsigned short)(u >> 16);
}

static __device__ __forceinline__ floatx4 mf(uintx4 a, short8_t b, floatx4 c) {
    union { uintx4 u; short8_t s; } x; x.u = a;
    return __builtin_amdgcn_mfma_f32_16x16x32_bf16(x.s, b, c, 0, 0, 0);
}

// 8 coherent 16B loads from one base with literal offsets, one asm block (counted externally)
#define A_LOAD8(d0,d1,d2,d3,d4,d5,d6,d7, base, O0,O1,O2,O3,O4,O5,O6,O7)       \
  asm volatile(                                                                \
    "global_load_dwordx4 %0, %8, off offset:" O0 " sc0 sc1\n\t"               \
    "global_load_dwordx4 %1, %8, off offset:" O1 " sc0 sc1\n\t"               \
    "global_load_dwordx4 %2, %8, off offset:" O2 " sc0 sc1\n\t"               \
    "global_load_dwordx4 %3, %8, off offset:" O3 " sc0 sc1\n\t"               \
    "global_load_dwordx4 %4, %8, off offset:" O4 " sc0 sc1\n\t"               \
    "global_load_dwordx4 %5, %8, off offset:" O5 " sc0 sc1\n\t"               \
    "global_load_dwordx4 %6, %8, off offset:" O6 " sc0 sc1\n\t"               \
    "global_load_dwordx4 %7, %8, off offset:" O7 " sc0 sc1"                   \
    : "=&v"(d0), "=&v"(d1), "=&v"(d2), "=&v"(d3),                              \
      "=&v"(d4), "=&v"(d5), "=&v"(d6), "=&v"(d7)                               \
    : "v"(base) : "memory")

#define VMWAIT(n) do { asm volatile("s_waitcnt vmcnt(" #n ")" ::: "memory");   \
                       __builtin_amdgcn_sched_barrier(0); } while (0)

// ---------------- prep: Wi->bf16; Wh->bf16 fragment-packed; h0->bf16 hbf[0]; zero flags ----
__global__ void prep_kernel(const float* __restrict__ Wi, const float* __restrict__ Wh,
                            const float* __restrict__ H0,
                            unsigned short* __restrict__ wi_bf,
                            unsigned short* __restrict__ whp,
                            unsigned int* __restrict__ flags,
                            unsigned int* __restrict__ hbf) {
    unsigned int idx = blockIdx.x * 256u + threadIdx.x;
    if (idx < 256u) flags[idx] = 0u;             // re-zeroed every launch (graph replay safe)
    if (idx < 1048576u) {
        wi_bf[idx] = f2bf(Wi[idx]);
    } else if (idx < 2097152u) {
        unsigned int o = idx - 1048576u;
        unsigned int e    = o & 7u;
        unsigned int l15  = (o >> 3) & 15u;
        unsigned int quad = (o >> 7) & 3u;
        unsigned int kt   = (o >> 9) & 31u;
        unsigned int colt = o >> 14;
        unsigned int col = colt * 16u + l15;
        unsigned int k   = kt * 32u + quad * 8u + e;
        whp[o] = f2bf(Wh[col * 1024u + k]);
    } else {
        // h0 -> hbf buffer 0 (row-major bf16 u32 pairs, grouped)
        unsigned int o2 = idx - 2097152u;        // [0, 131072)
        unsigned int c2  = o2 & 511u;            // u32 col-pair 0..511
        unsigned int row = o2 >> 9;              // global batch row 0..255
        unsigned int g   = row >> 5;
        unsigned int rl  = row & 31u;
        unsigned int lo = f2bf(H0[row * 1024u + c2 * 2u]);
        unsigned int hi = f2bf(H0[row * 1024u + c2 * 2u + 1u]);
        hbf[g * HBF_GRP_U32 + rl * 512u + c2] = lo | (hi << 16);
    }
}

// ---------------- xi = x @ Wi^T + bi  (M=65536, N=1024, K=1024) ---------------- (unchanged)
__global__ __launch_bounds__(256) void xi_gemm(
    const float* __restrict__ X,
    const unsigned short* __restrict__ Wi_bf,
    const float* __restrict__ Wi_b,
    float* __restrict__ Out) {
    __shared__ unsigned short As[128][40];
    __shared__ unsigned short Bs[128][40];

    int tid = threadIdx.x;
    int bx = blockIdx.x;
    int bm = bx >> 3, bn = bx & 7;
    int wave = tid >> 6, lane = tid & 63, l15 = lane & 15, quad = lane >> 4;
    int mw = (wave >> 1) * 64, nw = (wave & 1) * 64;

    floatx4 acc[4][4];
#pragma unroll
    for (int i = 0; i < 4; ++i)
#pragma unroll
        for (int j = 0; j < 4; ++j) acc[i][j] = (floatx4){0.f, 0.f, 0.f, 0.f};

    int srow = tid >> 1;
    int shalf = tid & 1;
    const float* ap = X + (long)(bm * 128 + srow) * 1024 + shalf * 16;
    const unsigned short* bp = Wi_bf + (long)(bn * 128 + srow) * 1024 + shalf * 16;
    unsigned short* asw = &As[srow][shalf * 16];
    unsigned short* bsw = &Bs[srow][shalf * 16];

    for (int kt = 0; kt < 32; ++kt) {
        float4 a0 = *(const float4*)(ap + 0);
        float4 a1 = *(const float4*)(ap + 4);
        float4 a2 = *(const float4*)(ap + 8);
        float4 a3 = *(const float4*)(ap + 12);
        short8_t b0 = *(const short8_t*)(bp);
        short8_t b1 = *(const short8_t*)(bp + 8);
        ap += 32; bp += 32;

        short8_t av0, av1;
        av0[0] = (short)f2bf(a0.x); av0[1] = (short)f2bf(a0.y);
        av0[2] = (short)f2bf(a0.z); av0[3] = (short)f2bf(a0.w);
        av0[4] = (short)f2bf(a1.x); av0[5] = (short)f2bf(a1.y);
        av0[6] = (short)f2bf(a1.z); av0[7] = (short)f2bf(a1.w);
        av1[0] = (short)f2bf(a2.x); av1[1] = (short)f2bf(a2.y);
        av1[2] = (short)f2bf(a2.z); av1[3] = (short)f2bf(a2.w);
        av1[4] = (short)f2bf(a3.x); av1[5] = (short)f2bf(a3.y);
        av1[6] = (short)f2bf(a3.z); av1[7] = (short)f2bf(a3.w);

        *(short8_t*)asw = av0;
        *(short8_t*)(asw + 8) = av1;
        *(short8_t*)bsw = b0;
        *(short8_t*)(bsw + 8) = b1;
        __syncthreads();

        short8_t aF[4], bF[4];
#pragma unroll
        for (int i = 0; i < 4; ++i) aF[i] = *(const short8_t*)&As[mw + i * 16 + l15][quad * 8];
#pragma unroll
        for (int i = 0; i < 4; ++i) bF[i] = *(const short8_t*)&Bs[nw + i * 16 + l15][quad * 8];
#pragma unroll
        for (int i = 0; i < 4; ++i)
#pragma unroll
            for (int j = 0; j < 4; ++j)
                acc[i][j] = __builtin_amdgcn_mfma_f32_16x16x32_bf16(aF[i], bF[j], acc[i][j], 0, 0, 0);
        __syncthreads();
    }

    long rowbase = (long)bm * 128 + mw + quad * 4;
    int colbase = bn * 128 + nw + l15;
#pragma unroll
    for (int j = 0; j < 4; ++j) {
        float bias = Wi_b[colbase + j * 16];
#pragma unroll
        for (int i = 0; i < 4; ++i)
#pragma unroll
            for (int r = 0; r < 4; ++r)
                Out[(rowbase + i * 16 + r) * 1024 + colbase + j * 16] = acc[i][j][r] + bias;
    }
}

// ---------------- recurrent scan v4: zero-LDS, A-direct-from-MALL, B-in-registers ----------
// 8 groups (32 rows) x 32 col-WGs; WG = 4 waves, wave (wr,wc) owns a 16x16 tile.
// Per step per wave: 32 coherent dwordx4 A-loads (sc0 sc1) software-pipelined in 4 batches
// with counted vmcnt; 32 MFMAs with B held in registers for the whole kernel; epilogue;
// distributed flag barrier (per-WG flag store + all-wave 32-flag poll). No LDS at all.
__global__ __launch_bounds__(256, 1) void rnn_scan3(
    float* __restrict__ IO,                       // xi in, h out (in-place)
    const unsigned short* __restrict__ whp,       // fragment-packed Wh bf16
    const float* __restrict__ Wh_b,
    unsigned int* __restrict__ flags,
    unsigned int* __restrict__ hbf) {
    const int bid = blockIdx.x;
    const int g   = bid & 7;                      // batch group
    const int cg  = bid >> 3;                     // col group
    const int tid = threadIdx.x;
    const int wave = tid >> 6, lane = tid & 63, l15 = lane & 15, quad = lane >> 4;
    const int wr = wave >> 1, wc = wave & 1;

    // ---- B fragments for all 256 steps: 32 x short8 = 128 VGPRs, loaded once ----
    short8_t bfr[32];
    {
        const unsigned short* wbase = whp + (unsigned)(cg * 2 + wc) * 16384u + (unsigned)lane * 8u;
#pragma unroll
        for (int kt = 0; kt < 32; ++kt)
            bfr[kt] = *(const short8_t*)(wbase + kt * 512);
    }

    const int col_g = cg * 32 + wc * 16 + l15;
    const float bias = Wh_b[col_g];
    const int rowl0 = wr * 16 + quad * 4;
    const unsigned cph = (unsigned)(col_g >> 1);

    // A base (byte) per buffer: row (wr*16+l15), k-chunk quad*16; kt advances by 64 B (imm)
    const unsigned rowoff = (unsigned)((wr * 16 + l15) * 2048 + quad * 16);
    const char* aB0 = (const char*)hbf + (unsigned)g * 65536u + rowoff;
    const char* aB1 = aB0 + 524288u;

    unsigned int* fl = flags + (unsigned)g * 32u;

    long ob = (long)(g * 32 + rowl0) * 1024 + col_g;

    // drain all compiler-issued loads so asm vmcnt counting starts clean
    asm volatile("s_waitcnt vmcnt(0)" ::: "memory");

    for (int t = 0; t < TSTEPS; ++t) {
        const char* ap = (t & 1) ? aB1 : aB0;
        uintx4 r0, r1, r2, r3, r4, r5, r6, r7;
        uintx4 s0, s1, s2, s3, s4, s5, s6, s7;

        floatx4 acc0 = (floatx4){0.f, 0.f, 0.f, 0.f};
        floatx4 acc1 = (floatx4){0.f, 0.f, 0.f, 0.f};

        A_LOAD8(r0,r1,r2,r3,r4,r5,r6,r7, ap, "0","64","128","192","256","320","384","448");
        A_LOAD8(s0,s1,s2,s3,s4,s5,s6,s7, ap, "512","576","640","704","768","832","896","960");

        VMWAIT(8);                                // batch0 ready (batch1 in flight)
        acc0 = mf(r0, bfr[0],  acc0); acc1 = mf(r1, bfr[1],  acc1);
        acc0 = mf(r2, bfr[2],  acc0); acc1 = mf(r3, bfr[3],  acc1);
        acc0 = mf(r4, bfr[4],  acc0); acc1 = mf(r5, bfr[5],  acc1);
        acc0 = mf(r6, bfr[6],  acc0); acc1 = mf(r7, bfr[7],  acc1);

        A_LOAD8(r0,r1,r2,r3,r4,r5,r6,r7, ap, "1024","1088","1152","1216","1280","1344","1408","1472");
        VMWAIT(8);                                // batch1 ready (batch2 in flight)
        acc0 = mf(s0, bfr[8],  acc0); acc1 = mf(s1, bfr[9],  acc1);
        acc0 = mf(s2, bfr[10], acc0); acc1 = mf(s3, bfr[11], acc1);
        acc0 = mf(s4, bfr[12], acc0); acc1 = mf(s5, bfr[13], acc1);
        acc0 = mf(s6, bfr[14], acc0); acc1 = mf(s7, bfr[15], acc1);

        A_LOAD8(s0,s1,s2,s3,s4,s5,s6,s7, ap, "1536","1600","1664","1728","1792","1856","1920","1984");
        // xi loads folded into the same counted stream (plain cached: IO written by xi_gemm)
        float x0, x1, x2, x3;
        {
            const float* p0 = IO + ob;
            asm volatile(
                "global_load_dword %0, %4, off\n\t"
                "global_load_dword %1, %5, off\n\t"
                "global_load_dword %2, %6, off\n\t"
                "global_load_dword %3, %7, off"
                : "=&v"(x0), "=&v"(x1), "=&v"(x2), "=&v"(x3)
                : "v"(p0), "v"(p0 + 1024), "v"(p0 + 2048), "v"(p0 + 3072)
                : "memory");
        }

        VMWAIT(12);                               // batch2 ready (batch3 + xi in flight)
        acc0 = mf(r0, bfr[16], acc0); acc1 = mf(r1, bfr[17], acc1);
        acc0 = mf(r2, bfr[18], acc0); acc1 = mf(r3, bfr[19], acc1);
        acc0 = mf(r4, bfr[20], acc0); acc1 = mf(r5, bfr[21], acc1);
        acc0 = mf(r6, bfr[22], acc0); acc1 = mf(r7, bfr[23], acc1);

        VMWAIT(4);                                // batch3 ready (xi in flight)
        acc0 = mf(s0, bfr[24], acc0); acc1 = mf(s1, bfr[25], acc1);
        acc0 = mf(s2, bfr[26], acc0); acc1 = mf(s3, bfr[27], acc1);
        acc0 = mf(s4, bfr[28], acc0); acc1 = mf(s5, bfr[29], acc1);
        acc0 = mf(s6, bfr[30], acc0); acc1 = mf(s7, bfr[31], acc1);

        VMWAIT(0);                                // xi ready
        floatx4 aa = acc0 + acc1;
        float hv0 = tanhf(aa[0] + x0 + bias);
        float hv1 = tanhf(aa[1] + x1 + bias);
        float hv2 = tanhf(aa[2] + x2 + bias);
        float hv3 = tanhf(aa[3] + x3 + bias);
        {
            const float* p0 = IO + ob;
            asm volatile("global_store_dword %0, %1, off" :: "v"(p0),        "v"(hv0) : "memory");
            asm volatile("global_store_dword %0, %1, off" :: "v"(p0 + 1024), "v"(hv1) : "memory");
            asm volatile("global_store_dword %0, %1, off" :: "v"(p0 + 2048), "v"(hv2) : "memory");
            asm volatile("global_store_dword %0, %1, off" :: "v"(p0 + 3072), "v"(hv3) : "memory");
        }

        if (t < TSTEPS - 1) {
            // ---- publish h(t+1) as bf16 u32 pairs (coherent write-through) ----
            unsigned int b0 = (unsigned int)f2bf(hv0);
            unsigned int b1 = (unsigned int)f2bf(hv1);
            unsigned int b2 = (unsigned int)f2bf(hv2);
            unsigned int b3 = (unsigned int)f2bf(hv3);
            unsigned int q0 = (unsigned int)__shfl_xor((int)b0, 1);
            unsigned int q1 = (unsigned int)__shfl_xor((int)b1, 1);
            unsigned int q2 = (unsigned int)__shfl_xor((int)b2, 1);
            unsigned int q3 = (unsigned int)__shfl_xor((int)b3, 1);
            unsigned int* dpb = hbf + (unsigned)((t + 1) & 1) * HBF_BUF_U32
                                    + (unsigned)g * HBF_GRP_U32;
            if (!(lane & 1)) {                    // even lane: rows r=0,1 (own col low)
                unsigned int* w0 = dpb + (rowl0 + 0) * 512 + cph;
                unsigned int v0 = b0 | (q0 << 16), v1 = b1 | (q1 << 16);
                asm volatile("global_store_dword %0, %1, off sc0 sc1" :: "v"(w0),       "v"(v0) : "memory");
                asm volatile("global_store_dword %0, %1, off sc0 sc1" :: "v"(w0 + 512), "v"(v1) : "memory");
            } else {                              // odd lane: rows r=2,3 (partner col low)
                unsigned int* w2 = dpb + (rowl0 + 2) * 512 + cph;
                unsigned int v2 = q2 | (b2 << 16), v3 = q3 | (b3 << 16);
                asm volatile("global_store_dword %0, %1, off sc0 sc1" :: "v"(w2),       "v"(v2) : "memory");
                asm volatile("global_store_dword %0, %1, off sc0 sc1" :: "v"(w2 + 512), "v"(v3) : "memory");
            }

            // ---- release: h stores acked at coherence point, then flag ----
            asm volatile("s_waitcnt vmcnt(0)" ::: "memory");
            __syncthreads();                      // all 4 waves' publishes acked
            if (tid == 0)
                __hip_atomic_store(fl + cg, (unsigned)(t + 1),
                                   __ATOMIC_RELAXED, __HIP_MEMORY_SCOPE_AGENT);
            // ---- all-wave poll of the 32 group flags (no second barrier) ----
            const unsigned tgt = (unsigned)(t + 1);
            while (1) {
                unsigned f = __hip_atomic_load(fl + (lane & 31),
                                               __ATOMIC_RELAXED, __HIP_MEMORY_SCOPE_AGENT);
                if (__all((int)(f >= tgt))) break;
                __builtin_amdgcn_s_sleep(1);
            }
        }
        ob += (long)BATCH * HID;
    }
}

extern "C" void kernel_launch(void* const* d_in, const int* in_sizes, int n_in,
                              void* d_out, int out_size, void* d_ws, size_t ws_size,
                              hipStream_t stream) {
    const float* x    = (const float*)d_in[0];
    const float* h0   = (const float*)d_in[1];
    const float* Wi_w = (const float*)d_in[2];
    const float* Wi_b = (const float*)d_in[3];
    const float* Wh_w = (const float*)d_in[4];
    const float* Wh_b = (const float*)d_in[5];
    float* out = (float*)d_out;
    char* ws = (char*)d_ws;
    unsigned short* wi_bf = (unsigned short*)(ws + WS_WI);
    unsigned short* whp   = (unsigned short*)(ws + WS_WHP);
    unsigned int*   bar   = (unsigned int*)(ws + WS_BAR);
    unsigned int*   hbf   = (unsigned int*)(ws + WS_HBF);

    prep_kernel<<<8704, 256, 0, stream>>>(Wi_w, Wh_w, h0, wi_bf, whp, bar, hbf);
    xi_gemm<<<4096, 256, 0, stream>>>(x, wi_bf, Wi_b, out);
    // 256 WGs == CU count -> 1 WG/CU co-residency for the flag barrier.
    rnn_scan3<<<256, 256, 0, stream>>>(out, whp, Wh_b, bar, hbf);
}